// Round 1
// 725.228 us; speedup vs baseline: 1.1825x; 1.1825x over previous
//
#include <hip/hip_runtime.h>
#include <cstdint>

// ============================================================================
// TripleAdaptiveQuantizerV6 — round 6: barrier-free per-wave k2.
//
// R5 post-mortem: k2 = 608us, VALUBusy 54%, occupancy 23%. Structure was
// barrier-bound: 4 m's serial per block, 20 __syncthreads, 4x4 tiles
// (16 FMA per 2 ds_read_b128), phase A on 1/4 waves. R6 k2: each wave owns
// one m end-to-end, ZERO barriers after weight staging. 8x8 register tiles
// (64 FMA per 2 ds_read_b128), in-place 64x64 XOR-swizzled act buffer
// (16KB/wave, reads precede writes in wave program order; DS in-order per
// wave), weights pre-transposed by k0w into the O_Hq out region (k3
// overwrites it later) and streamed through L1. Every output keeps the
// exact bias + i-ascending fmaf chain and f64 feature op order of R5 ->
// ly/lh/ld bit-identical -> flags / kfix / outputs unchanged.
// ============================================================================

#define JAX_PARTITIONABLE 1

constexpr int BL = 64 * 256;  // 16384 (B*L)

// Output offsets (floats)
constexpr long long O_vq  = 0;
constexpr long long O_Hq  = 2097152;
constexpr long long O_yq  = 18874368;
constexpr long long O_eb  = 19136512;
constexpr long long O_wy  = 20185088;
constexpr long long O_wH  = 20283392;
constexpr long long O_wd  = 26574848;
constexpr long long O_yba = 32866304;
constexpr long long O_Hbl = 32882688;
constexpr long long O_dbl = 33931264;

// flag stash inside the v_q region (k4 overwrites all of v_q afterwards)
constexpr long long F_SAMPLE = 0;        // 1048576 bytes, 1 per (m,k)
constexpr long long F_M      = 1048576;  // 16384 bytes, 1 per m

// transposed-weight stash inside the H_q region (k3 overwrites afterwards):
// [0..576) w1T [i<9][j], [576..4672) w2T [i][j], [4672..8768) w3T [i][j],
// [8768..10816) whT [i][r<32] (r>=18 zero)
#define MARGIN_THETA 3e-4

// ---------------------------------------------------------------- threefry
__device__ __forceinline__ uint32_t rotl32(uint32_t v, int d) {
  return (v << d) | (v >> (32 - d));
}

__device__ __forceinline__ void threefry2x32(uint32_t k0, uint32_t k1,
                                             uint32_t x0, uint32_t x1,
                                             uint32_t& o0, uint32_t& o1) {
  const uint32_t ks2 = k0 ^ k1 ^ 0x1BD11BDAu;
  x0 += k0; x1 += k1;
  x0 += x1; x1 = rotl32(x1, 13); x1 ^= x0;
  x0 += x1; x1 = rotl32(x1, 15); x1 ^= x0;
  x0 += x1; x1 = rotl32(x1, 26); x1 ^= x0;
  x0 += x1; x1 = rotl32(x1, 6);  x1 ^= x0;
  x0 += k1; x1 += ks2 + 1u;
  x0 += x1; x1 = rotl32(x1, 17); x1 ^= x0;
  x0 += x1; x1 = rotl32(x1, 29); x1 ^= x0;
  x0 += x1; x1 = rotl32(x1, 16); x1 ^= x0;
  x0 += x1; x1 = rotl32(x1, 24); x1 ^= x0;
  x0 += ks2; x1 += k0 + 2u;
  x0 += x1; x1 = rotl32(x1, 13); x1 ^= x0;
  x0 += x1; x1 = rotl32(x1, 15); x1 ^= x0;
  x0 += x1; x1 = rotl32(x1, 26); x1 ^= x0;
  x0 += x1; x1 = rotl32(x1, 6);  x1 ^= x0;
  x0 += k0; x1 += k1 + 3u;
  x0 += x1; x1 = rotl32(x1, 17); x1 ^= x0;
  x0 += x1; x1 = rotl32(x1, 29); x1 ^= x0;
  x0 += x1; x1 = rotl32(x1, 16); x1 ^= x0;
  x0 += x1; x1 = rotl32(x1, 24); x1 ^= x0;
  x0 += k1; x1 += ks2 + 4u;
  x0 += x1; x1 = rotl32(x1, 13); x1 ^= x0;
  x0 += x1; x1 = rotl32(x1, 15); x1 ^= x0;
  x0 += x1; x1 = rotl32(x1, 26); x1 ^= x0;
  x0 += x1; x1 = rotl32(x1, 6);  x1 ^= x0;
  x0 += ks2; x1 += k0 + 5u;
  o0 = x0; o1 = x1;
}

__device__ __forceinline__ uint32_t jax_randbits(uint32_t k0, uint32_t k1,
                                                 uint32_t e, uint32_t size) {
#if JAX_PARTITIONABLE
  (void)size;
  uint32_t o0, o1;
  threefry2x32(k0, k1, 0u, e, o0, o1);
  return o0 ^ o1;
#else
  const uint32_t half = size >> 1;
  uint32_t o0, o1;
  if (e < half) { threefry2x32(k0, k1, e, e + half, o0, o1); return o0; }
  threefry2x32(k0, k1, e - half, e, o0, o1); return o1;
#endif
}

// exact f32 replication of jax.random.uniform(minval=1e-10, maxval=1.0)
__device__ __forceinline__ float bits_to_unif(uint32_t bits) {
  float f = __uint_as_float((bits >> 9) | 0x3f800000u) - 1.0f;
  return fmaxf(1e-10f, f + 1e-10f);
}

// ---------------------------------------------------------------- helpers
__device__ __forceinline__ double wave_sum_f64(double x) {
#pragma unroll
  for (int off = 32; off > 0; off >>= 1) x += __shfl_xor(x, off);
  return x;
}

__device__ __forceinline__ void argmax_gap6(const double* s, int& arg, double& gap) {
  int a = 0;
#pragma unroll
  for (int j = 1; j < 6; ++j) if (s[j] > s[a]) a = j;
  double second = -1e300;
#pragma unroll
  for (int j = 0; j < 6; ++j) if (j != a && s[j] > second) second = s[j];
  arg = a; gap = s[a] - second;
}

__device__ __forceinline__ float idx_to_bits(int i) {
  return (float)((i < 4) ? 2 * (i + 1) : (i == 4 ? 12 : 16));
}

#define WSYNC() asm volatile("s_waitcnt lgkmcnt(0)" ::: "memory")

// ---------------------------------------------------------------- K0: ss + keys
__global__ void k0_setup(const float* __restrict__ sy, const float* __restrict__ sH,
                         const float* __restrict__ sd, float* __restrict__ ss,
                         uint32_t* __restrict__ keys) {
  const int t = threadIdx.x;
  if (t < 18) {
    const int tensor = t / 6, i = t % 6;
    const int qp_[6] = {1, 7, 31, 127, 2047, 32767};
    const long long sizes[3] = {262144LL, 16777216LL, 2097152LL};  // y, H, v
    const float* sarr = tensor == 0 ? sy : (tensor == 1 ? sH : sd);
    const double g64 = 1.0 / sqrt((double)(sizes[tensor] * (long long)qp_[i]));
    const float g32 = (float)g64;
    const float s = sarr[i];
    const float t1 = s * g32;
    ss[t] = t1 + (s - t1);  // _grad_scale forward, exact f32 sequence
  }
#if JAX_PARTITIONABLE
  if (t >= 32 && t < 35) {
    uint32_t o0, o1;
    threefry2x32(0u, 42u, 0u, (uint32_t)(t - 32), o0, o1);
    keys[(t - 32) * 2 + 0] = o0;
    keys[(t - 32) * 2 + 1] = o1;
  }
#else
  if (t == 32) {
    uint32_t a0, b0, a1, b1, a2, b2;
    threefry2x32(0u, 42u, 0u, 3u, a0, b0);
    threefry2x32(0u, 42u, 1u, 4u, a1, b1);
    threefry2x32(0u, 42u, 2u, 5u, a2, b2);
    keys[0] = a0; keys[1] = a1;
    keys[2] = a2; keys[3] = b0;
    keys[4] = b1; keys[5] = b2;
  }
#endif
}

// ---------------------------------------------------------------- K0w: weightT
// Transposed weights -> out+O_Hq (k3 fully overwrites that region later).
__global__ void k0w_transpose(const float* __restrict__ w1, const float* __restrict__ w2,
                              const float* __restrict__ w3, const float* __restrict__ wy,
                              const float* __restrict__ wh, const float* __restrict__ wd,
                              float* __restrict__ wsT) {
  const int t = blockIdx.x * blockDim.x + threadIdx.x;  // 4096 threads
  for (int idx = t; idx < 576; idx += 4096)
    wsT[idx] = w1[(idx & 63) * 9 + (idx >> 6)];
  for (int idx = t; idx < 4096; idx += 4096) {
    wsT[576 + idx]  = w2[(idx & 63) * 64 + (idx >> 6)];
    wsT[4672 + idx] = w3[(idx & 63) * 64 + (idx >> 6)];
  }
  for (int idx = t; idx < 2048; idx += 4096) {
    const int i = idx >> 5, r = idx & 31;
    wsT[8768 + idx] = (r < 6) ? wy[r * 64 + i]
                    : (r < 12) ? wh[(r - 6) * 64 + i]
                    : (r < 18) ? wd[(r - 12) * 64 + i] : 0.0f;
  }
}

// ---------------------------------------------------------------- K1: hp_mean
__global__ __launch_bounds__(128) void k1a_hpower_partial(
    const float* __restrict__ Hm, double* __restrict__ partial) {
  const int blk = blockIdx.x;       // 512 = 64 b * 8 l-chunks
  const int b = blk >> 3, lc = blk & 7;
  const int t = threadIdx.x;        // 128 = (k,c)
  const float* base = Hm + (size_t)(b * 256 + lc * 32) * 1024;
  double acc = 0.0;
  for (int l = 0; l < 32; ++l) {
#pragma unroll
    for (int n = 0; n < 8; ++n) {
      const float x = base[(size_t)l * 1024 + n * 128 + t];
      acc = fma((double)x, (double)x, acc);
    }
  }
  const double other = __shfl_xor(acc, 1);
  if ((t & 1) == 0) partial[(size_t)blk * 64 + (t >> 1)] = acc + other;
}

__global__ void k1b_hpmean(const double* __restrict__ partial,
                           double* __restrict__ hp_mean) {
  const int id = blockIdx.x * blockDim.x + threadIdx.x;  // 4096 = b*64+k
  if (id >= 4096) return;
  const int b = id >> 6, k = id & 63;
  double s = 0.0;
#pragma unroll
  for (int lc = 0; lc < 8; ++lc) s += partial[(size_t)(b * 8 + lc) * 64 + k];
  hp_mean[id] = s * (1.0 / 256.0);
}

// ---------------------------------------------------------------- wave GEMM
// One WAVE computes out[j=64][k=64] = act(bias + W^T x) in-place in its own
// LDS buffer. 8x8 register tile per lane. act layout: float index
// f = (row*64+k) ^ (((row>>3)&7)<<2)  (16B-chunk XOR swizzle; reads are
// whole-row -> conflict-free; writes spread across bank groups).
// Weights from GLOBAL (L1-cached), layout [i][j] stride 64.
// Per-output chain: acc = bias[j]; fmaf(w, x, acc) ascending i  — identical
// numerics to R5's gemm64.
template <int NI, bool RELU>
__device__ __forceinline__ void wgemm(float* act, const float* __restrict__ Wg,
                                      const float* __restrict__ bias, int lane) {
  const int a = lane >> 3, b = lane & 7;
  const int j0 = a * 8, k0 = b * 8;
  float acc[64];
  {
    const float4 bj0 = *(const float4*)(bias + j0);
    const float4 bj1 = *(const float4*)(bias + j0 + 4);
    const float bjv[8] = {bj0.x, bj0.y, bj0.z, bj0.w, bj1.x, bj1.y, bj1.z, bj1.w};
#pragma unroll
    for (int jj = 0; jj < 8; ++jj)
#pragma unroll
      for (int kk = 0; kk < 8; ++kk) acc[jj * 8 + kk] = bjv[jj];
  }
#pragma unroll 4
  for (int i = 0; i < NI; ++i) {
    const int sw = (i * 64 + k0) ^ (((i >> 3) & 7) << 2);
    const float4 xa = *(const float4*)(act + sw);
    const float4 xb = *(const float4*)(act + (sw ^ 4));
    const float4 wa = *(const float4*)(Wg + i * 64 + j0);
    const float4 wb = *(const float4*)(Wg + i * 64 + j0 + 4);
    const float xv[8] = {xa.x, xa.y, xa.z, xa.w, xb.x, xb.y, xb.z, xb.w};
    const float wv[8] = {wa.x, wa.y, wa.z, wa.w, wb.x, wb.y, wb.z, wb.w};
#pragma unroll
    for (int jj = 0; jj < 8; ++jj)
#pragma unroll
      for (int kk = 0; kk < 8; ++kk)
        acc[jj * 8 + kk] = fmaf(wv[jj], xv[kk], acc[jj * 8 + kk]);
  }
  asm volatile("" ::: "memory");  // keep all reads before in-place writes
#pragma unroll
  for (int jj = 0; jj < 8; ++jj) {
    const int j = j0 + jj;                       // j>>3 == a for jj<8
    const int swo = (j * 64 + k0) ^ ((a & 7) << 2);
    float4 r0, r1;
    r0.x = acc[jj * 8 + 0]; r0.y = acc[jj * 8 + 1];
    r0.z = acc[jj * 8 + 2]; r0.w = acc[jj * 8 + 3];
    r1.x = acc[jj * 8 + 4]; r1.y = acc[jj * 8 + 5];
    r1.z = acc[jj * 8 + 6]; r1.w = acc[jj * 8 + 7];
    if (RELU) {
      r0.x = fmaxf(r0.x, 0.0f); r0.y = fmaxf(r0.y, 0.0f);
      r0.z = fmaxf(r0.z, 0.0f); r0.w = fmaxf(r0.w, 0.0f);
      r1.x = fmaxf(r1.x, 0.0f); r1.y = fmaxf(r1.y, 0.0f);
      r1.z = fmaxf(r1.z, 0.0f); r1.w = fmaxf(r1.w, 0.0f);
    }
    *(float4*)(act + swo) = r0;
    *(float4*)(act + (swo ^ 4)) = r1;
  }
}

// heads per wave: out[r<20][k=64], 5r x 4k tile per lane. whT in LDS [i][r<32].
// Writes headP[k*20+r] (plain layout) INTO the act buffer (act is dead).
// Per-output chain: acc = hb[r]; fmaf(x, w, acc) ascending i — identical
// numerics to R5's heads20.
__device__ __forceinline__ void wheads(float* buf, const float* __restrict__ whT,
                                       const float* __restrict__ hb, int lane) {
  const int r0 = (lane >> 4) * 5;
  const int k0 = (lane & 15) * 4;
  float acc[20];
#pragma unroll
  for (int q = 0; q < 5; ++q) {
    const float bq = hb[r0 + q];
#pragma unroll
    for (int kk = 0; kk < 4; ++kk) acc[q * 4 + kk] = bq;
  }
#pragma unroll 4
  for (int i = 0; i < 64; ++i) {
    const int sw = (i * 64 + k0) ^ (((i >> 3) & 7) << 2);
    const float4 x = *(const float4*)(buf + sw);
#pragma unroll
    for (int q = 0; q < 5; ++q) {
      const float w = whT[i * 32 + r0 + q];
      acc[q * 4 + 0] = fmaf(x.x, w, acc[q * 4 + 0]);
      acc[q * 4 + 1] = fmaf(x.y, w, acc[q * 4 + 1]);
      acc[q * 4 + 2] = fmaf(x.z, w, acc[q * 4 + 2]);
      acc[q * 4 + 3] = fmaf(x.w, w, acc[q * 4 + 3]);
    }
  }
  asm volatile("" ::: "memory");  // all act reads before headP overlay writes
#pragma unroll
  for (int q = 0; q < 5; ++q)
#pragma unroll
    for (int kk = 0; kk < 4; ++kk)
      buf[(k0 + kk) * 20 + r0 + q] = acc[q * 4 + kk];
}

// ---------------------------------------------------------------- K2: main
// 4 m per 256-thread block, ONE WAVE PER M, no barriers after staging.
__global__ __launch_bounds__(256, 2) void k2_main(
    const float* __restrict__ v, const float* __restrict__ Hm,
    const float* __restrict__ y, const float* __restrict__ snr,
    const float* __restrict__ b1, const float* __restrict__ b2,
    const float* __restrict__ b3, const float* __restrict__ by,
    const float* __restrict__ bh, const float* __restrict__ bd,
    const float* __restrict__ wsT, const double* __restrict__ hp_mean,
    const uint32_t* __restrict__ keys, float* __restrict__ out) {
  const int t = threadIdx.x;
  const int lane = t & 63;
  const int wvx = t >> 6;
  const int m = blockIdx.x * 4 + wvx;

  __shared__ __align__(16) float smem[18464];  // 73856 B -> 2 blocks/CU
  float* whT = smem + 16384;  // 2048: [i][r<32]
  float* hb  = smem + 18432;  // 32
  float* buf = smem + wvx * 4096;  // this wave's 64x64 act (swizzled)

  for (int idx = t; idx < 2048; idx += 256) whT[idx] = wsT[8768 + idx];
  if (t < 20)
    hb[t] = (t < 6) ? by[t] : (t < 12) ? bh[t - 6] : (t < 18) ? bd[t - 12] : 0.0f;
  __syncthreads();  // the only block barrier

  // ---- features (per wave; f64 op order identical to R5) ----
  {
    const float2* Hp = (const float2*)Hm + (size_t)m * 512;
    double aw[4];
#pragma unroll
    for (int w = 0; w < 4; ++w) {
      double acc = 0.0;
#pragma unroll
      for (int nn = 0; nn < 2; ++nn) {
        const float2 h2v = Hp[(2 * w + nn) * 64 + lane];
        acc = fma((double)h2v.x, (double)h2v.x, acc);
        acc = fma((double)h2v.y, (double)h2v.y, acc);
      }
      aw[w] = acc;
    }
    const double hp = ((aw[0] + aw[1]) + aw[2]) + aw[3];
    const double tp = wave_sum_f64(hp);
    double ypart = 0.0;
    if (lane < 16) { const double yv = (double)y[m * 16 + lane]; ypart = yv * yv; }
    const double yp = wave_sum_f64(ypart);
    const float2 vv = ((const float2*)v)[m * 64 + lane];
    const float snrv = snr[m * 64 + lane];
    const double hpm = hp_mean[(m >> 8) * 64 + lane];
    float f[9];
    f[0] = (float)vv.x;
    f[1] = (float)vv.y;
    f[2] = snrv;
    f[3] = (float)hp;
    f[4] = (float)hpm;
    f[5] = (float)log1p(hp / ((tp - hp) + 1e-10));
    f[6] = (float)log1p(tp);
    f[7] = (float)log1p(yp);
    f[8] = (float)sqrt(fma((double)vv.x, (double)vv.x,
                           fma((double)vv.y, (double)vv.y, 1e-10)));
#pragma unroll
    for (int i = 0; i < 9; ++i)
      buf[(i * 64 + lane) ^ (((i >> 3) & 7) << 2)] = f[i];
  }
  WSYNC();
  wgemm<9, true>(buf, wsT, b1, lane);
  WSYNC();
  wgemm<64, true>(buf, wsT + 576, b2, lane);
  WSYNC();
  wgemm<64, true>(buf, wsT + 4672, b3, lane);
  WSYNC();
  wheads(buf, whT, hb, lane);
  WSYNC();

  float ly[6], lh[6], ld[6];
#pragma unroll
  for (int j = 0; j < 6; ++j) {
    ly[j] = buf[lane * 20 + j];
    lh[j] = buf[lane * 20 + 6 + j];
    ld[j] = buf[lane * 20 + 12 + j];
  }

  // ---- phase C: selection (verbatim R5) ----
  const int k = lane;

  const uint32_t g1k0 = keys[0], g1k1 = keys[1];
  const uint32_t g2k0 = keys[2], g2k1 = keys[3];
  const uint32_t g3k0 = keys[4], g3k1 = keys[5];

  double sH[6], sD[6];
  const uint32_t eH = (uint32_t)(m * 64 + k) * 6u;
#pragma unroll
  for (int j = 0; j < 6; ++j) {
    const float u = bits_to_unif(jax_randbits(g2k0, g2k1, eH + j, 6291456u));
    sH[j] = (double)lh[j] + (double)(-logf(-logf(u)));
  }
#pragma unroll
  for (int j = 0; j < 6; ++j) {
    const float u = bits_to_unif(jax_randbits(g3k0, g3k1, eH + j, 6291456u));
    sD[j] = (double)ld[j] + (double)(-logf(-logf(u)));
  }
  int argH, argD; double gapH, gapD;
  argmax_gap6(sH, argH, gapH);
  argmax_gap6(sD, argD, gapD);

  double lysum[6];
#pragma unroll
  for (int j = 0; j < 6; ++j) lysum[j] = wave_sum_f64((double)ly[j]);

  int argY = 0; double gapY = 1e30;
  if (k == 0) {
    double sY[6];
#pragma unroll
    for (int j = 0; j < 6; ++j) {
      const float u = bits_to_unif(jax_randbits(g1k0, g1k1, (uint32_t)(m * 6 + j), 98304u));
      sY[j] = lysum[j] * (1.0 / 64.0) - log(-log((double)u));
    }
    argmax_gap6(sY, argY, gapY);
  }
  const int needY = __shfl((k == 0 && gapY < MARGIN_THETA) ? 1 : 0, 0);
  const bool fH = gapH < MARGIN_THETA;
  const bool fD = gapD < MARGIN_THETA;

  uint8_t* flags = (uint8_t*)(out + O_vq);
  flags[F_SAMPLE + (size_t)m * 64 + k] = (uint8_t)((fH ? 1 : 0) | (fD ? 2 : 0));
  const bool anyHD = __ballot(fH || fD) != 0ull;
  if (k == 0)
    flags[F_M + m] = (uint8_t)(((anyHD || needY) ? 1 : 0) | (needY ? 2 : 0));

  argY = __shfl(argY, 0);

  const float bY = 16.0f * idx_to_bits(argY);   // 2*N*bits
  const float bH = 16.0f * idx_to_bits(argH);
  const float bD = 2.0f * idx_to_bits(argD);

  if (k == 0) {
    out[O_yba + m] = bY;
#pragma unroll
    for (int j = 0; j < 6; ++j) out[O_wy + m * 6 + j] = (j == argY) ? 1.0f : 0.0f;
  }
  out[O_Hbl + (size_t)m * 64 + k] = bH;
  out[O_dbl + (size_t)m * 64 + k] = bD;
  out[O_eb + (size_t)m * 64 + k] = (bY * 0.015625f + bH) + bD;
#pragma unroll
  for (int j = 0; j < 6; ++j) {
    out[O_wH + (size_t)(m * 64 + k) * 6 + j] = (j == argH) ? 1.0f : 0.0f;
    out[O_wd + (size_t)(m * 64 + k) * 6 + j] = (j == argD) ? 1.0f : 0.0f;
  }
}

// ---------------------------------------------------------------- f64 helpers
// f64 variant for kfix: weights f32 in LDS (exact convert), act f64 [i][k].
template <int NI>
__device__ __forceinline__ void gemm64_f64(const double* __restrict__ inT,
                                           const float* __restrict__ WT,
                                           const float* __restrict__ bias,
                                           double* __restrict__ outT, int t) {
  const int k0 = (t & 15) * 4;
  const int j0 = (t >> 4) * 4;
  double acc[16];
#pragma unroll
  for (int jj = 0; jj < 4; ++jj) {
    const double bj = (double)bias[j0 + jj];
#pragma unroll
    for (int kk = 0; kk < 4; ++kk) acc[jj * 4 + kk] = bj;
  }
#pragma unroll 8
  for (int i = 0; i < NI; ++i) {
    const double x0 = inT[i * 68 + k0 + 0];
    const double x1 = inT[i * 68 + k0 + 1];
    const double x2 = inT[i * 68 + k0 + 2];
    const double x3 = inT[i * 68 + k0 + 3];
    const float4 wf = *(const float4*)&WT[i * 64 + j0];
    const double w0 = (double)wf.x, w1 = (double)wf.y;
    const double w2 = (double)wf.z, w3 = (double)wf.w;
    acc[0]  = fma(w0, x0, acc[0]);
    acc[1]  = fma(w0, x1, acc[1]);
    acc[2]  = fma(w0, x2, acc[2]);
    acc[3]  = fma(w0, x3, acc[3]);
    acc[4]  = fma(w1, x0, acc[4]);
    acc[5]  = fma(w1, x1, acc[5]);
    acc[6]  = fma(w1, x2, acc[6]);
    acc[7]  = fma(w1, x3, acc[7]);
    acc[8]  = fma(w2, x0, acc[8]);
    acc[9]  = fma(w2, x1, acc[9]);
    acc[10] = fma(w2, x2, acc[10]);
    acc[11] = fma(w2, x3, acc[11]);
    acc[12] = fma(w3, x0, acc[12]);
    acc[13] = fma(w3, x1, acc[13]);
    acc[14] = fma(w3, x2, acc[14]);
    acc[15] = fma(w3, x3, acc[15]);
  }
#pragma unroll
  for (int jj = 0; jj < 4; ++jj) {
#pragma unroll
    for (int kk = 0; kk < 4; ++kk) {
      const double a = acc[jj * 4 + kk];
      outT[(j0 + jj) * 68 + k0 + kk] = a > 0.0 ? a : 0.0;  // same relu as ref
    }
  }
}

__device__ __forceinline__ void heads20_f64(const double* __restrict__ actT,
                                            const float* __restrict__ whT,
                                            const float* __restrict__ by,
                                            const float* __restrict__ bh,
                                            const float* __restrict__ bd,
                                            double* __restrict__ headP, int t) {
  const int k = t & 63, w = t >> 6;
  double acc[5];
#pragma unroll
  for (int q = 0; q < 5; ++q) {
    const int r = w + 4 * q;
    acc[q] = (r < 6) ? (double)by[r]
           : (r < 12) ? (double)bh[r - 6]
           : (r < 18) ? (double)bd[r - 12] : 0.0;
  }
#pragma unroll 8
  for (int i = 0; i < 64; ++i) {
    const double x = actT[i * 68 + k];
#pragma unroll
    for (int q = 0; q < 5; ++q)
      acc[q] = fma(x, (double)whT[(w + 4 * q) * 64 + i], acc[q]);
  }
#pragma unroll
  for (int q = 0; q < 5; ++q) {
    const int r = w + 4 * q;
    if (r < 18) headP[k * 20 + r] = acc[q];
  }
}

// ---------------------------------------------------------------- kfix
// 256-thread block handles 8 m's; per flagged m runs the f64 LDS-gemm MLP.
__global__ __launch_bounds__(256, 1) void kfix(
    const float* __restrict__ v, const float* __restrict__ Hm,
    const float* __restrict__ y, const float* __restrict__ snr,
    const float* __restrict__ w1, const float* __restrict__ b1,
    const float* __restrict__ w2, const float* __restrict__ b2,
    const float* __restrict__ w3, const float* __restrict__ b3,
    const float* __restrict__ wy, const float* __restrict__ by,
    const float* __restrict__ wh, const float* __restrict__ bh,
    const float* __restrict__ wd, const float* __restrict__ bd,
    const double* __restrict__ hp_mean, const uint32_t* __restrict__ keys,
    float* __restrict__ out) {
  const int t = threadIdx.x;
  const int lane = t & 63;
  const int wvx = t >> 6;
  const int m0 = blockIdx.x * 8;
  const uint8_t* flags = (const uint8_t*)(out + O_vq);

  __shared__ uint32_t mfs[8];
  __shared__ __align__(32) char smem[120064];
  float*  w1T     = (float*)smem;                 // 576 f  [i<9][j]
  float*  w2T     = (float*)(smem + 2304);        // 4096 f [i][j]
  float*  w3T     = (float*)(smem + 18688);       // 4096 f [i][j]
  float*  whT     = (float*)(smem + 35072);       // 1280 f [r<20][i]
  double* actA64  = (double*)(smem + 40192);      // 64x68 d [row][k]
  double* actB64  = (double*)(smem + 75008);      // 64x68 d
  double* headP64 = (double*)(smem + 109824);     // 64x20 d [k][20]
  double* hp4     = actB64;                       // alias (pre-L1 only)

  if (t < 8) mfs[t] = flags[F_M + m0 + t];
  __syncthreads();
  bool any = false;
#pragma unroll
  for (int i = 0; i < 8; ++i) any |= (mfs[i] != 0);
  if (!any) return;

  // stage weights once (same transposed layouts as R5)
  for (int idx = t; idx < 576; idx += 256) {
    const int i = idx >> 6, j = idx & 63;
    w1T[idx] = w1[j * 9 + i];
  }
  for (int idx = t; idx < 4096; idx += 256) {
    const int i = idx >> 6, j = idx & 63;
    w2T[idx] = w2[j * 64 + i];
    w3T[idx] = w3[j * 64 + i];
  }
  for (int idx = t; idx < 1280; idx += 256) {
    const int r = idx >> 6, i = idx & 63;
    whT[idx] = (r < 6) ? wy[r * 64 + i]
             : (r < 12) ? wh[(r - 6) * 64 + i]
             : (r < 18) ? wd[(r - 12) * 64 + i] : 0.0f;
  }

#pragma unroll 1
  for (int mi = 0; mi < 8; ++mi) {
    const uint32_t mf = mfs[mi];
    if (mf == 0) continue;  // block-uniform
    const int m = m0 + mi;

    // hp partials, identical op order to k2
    {
      const float2* Hp = (const float2*)Hm + (size_t)m * 512;
      double acc = 0.0;
#pragma unroll
      for (int nn = 0; nn < 2; ++nn) {
        const float2 h2v = Hp[(2 * wvx + nn) * 64 + lane];
        acc = fma((double)h2v.x, (double)h2v.x, acc);
        acc = fma((double)h2v.y, (double)h2v.y, acc);
      }
      __syncthreads();  // weights staged / prior-m reads done before actB reuse
      hp4[wvx * 64 + lane] = acc;
    }
    __syncthreads();

    // wave 0: f64 features -> actA64 rows 0..8
    if (t < 64) {
      const double hp = ((hp4[lane] + hp4[64 + lane]) + hp4[128 + lane]) + hp4[192 + lane];
      const double tp = wave_sum_f64(hp);
      double ypart = 0.0;
      if (lane < 16) { const double yv = (double)y[m * 16 + lane]; ypart = yv * yv; }
      const double yp = wave_sum_f64(ypart);
      const float2 vv = ((const float2*)v)[m * 64 + lane];
      const float snrv = snr[m * 64 + lane];
      const double hpm = hp_mean[(m >> 8) * 64 + lane];
      double f[9];
      f[0] = (double)vv.x;
      f[1] = (double)vv.y;
      f[2] = (double)snrv;
      f[3] = hp;
      f[4] = hpm;
      f[5] = log1p(hp / ((tp - hp) + 1e-10));
      f[6] = log1p(tp);
      f[7] = log1p(yp);
      f[8] = sqrt(fma((double)vv.x, (double)vv.x,
                      fma((double)vv.y, (double)vv.y, 1e-10)));
#pragma unroll
      for (int i = 0; i < 9; ++i) actA64[i * 68 + lane] = f[i];
    }
    __syncthreads();

    gemm64_f64<9>(actA64, w1T, b1, actB64, t);
    __syncthreads();
    gemm64_f64<64>(actB64, w2T, b2, actA64, t);
    __syncthreads();
    gemm64_f64<64>(actA64, w3T, b3, actB64, t);
    __syncthreads();
    heads20_f64(actB64, whT, by, bh, bd, headP64, t);
    __syncthreads();

    // wave 0: refine flagged selections
    if (t < 64) {
      const int k = lane;
      const uint8_t f = flags[F_SAMPLE + (size_t)m * 64 + k];
      double lyd[6], lhd[6], ldd[6];
#pragma unroll
      for (int j = 0; j < 6; ++j) {
        lyd[j] = headP64[k * 20 + j];
        lhd[j] = headP64[k * 20 + 6 + j];
        ldd[j] = headP64[k * 20 + 12 + j];
      }
      const uint32_t g1k0 = keys[0], g1k1 = keys[1];
      const uint32_t g2k0 = keys[2], g2k1 = keys[3];
      const uint32_t g3k0 = keys[4], g3k1 = keys[5];
      const uint32_t eH = (uint32_t)(m * 64 + k) * 6u;

      float bHf, bDf;
      if (f & 1) {
        double s2[6];
#pragma unroll
        for (int j = 0; j < 6; ++j) {
          const float u = bits_to_unif(jax_randbits(g2k0, g2k1, eH + j, 6291456u));
          s2[j] = lhd[j] - log(-log((double)u));
        }
        int argH; double g; argmax_gap6(s2, argH, g);
        bHf = 16.0f * idx_to_bits(argH);
        out[O_Hbl + (size_t)m * 64 + k] = bHf;
#pragma unroll
        for (int j = 0; j < 6; ++j)
          out[O_wH + (size_t)(m * 64 + k) * 6 + j] = (j == argH) ? 1.0f : 0.0f;
      } else {
        bHf = out[O_Hbl + (size_t)m * 64 + k];
      }
      if (f & 2) {
        double s2[6];
#pragma unroll
        for (int j = 0; j < 6; ++j) {
          const float u = bits_to_unif(jax_randbits(g3k0, g3k1, eH + j, 6291456u));
          s2[j] = ldd[j] - log(-log((double)u));
        }
        int argD; double g; argmax_gap6(s2, argD, g);
        bDf = 2.0f * idx_to_bits(argD);
        out[O_dbl + (size_t)m * 64 + k] = bDf;
#pragma unroll
        for (int j = 0; j < 6; ++j)
          out[O_wd + (size_t)(m * 64 + k) * 6 + j] = (j == argD) ? 1.0f : 0.0f;
      } else {
        bDf = out[O_dbl + (size_t)m * 64 + k];
      }

      float bYf;
      if (mf & 2) {
        double lys2[6];
#pragma unroll
        for (int j = 0; j < 6; ++j) lys2[j] = wave_sum_f64(lyd[j]);
        int argY = 0;
        if (k == 0) {
          double s2[6];
#pragma unroll
          for (int j = 0; j < 6; ++j) {
            const float u = bits_to_unif(jax_randbits(g1k0, g1k1, (uint32_t)(m * 6 + j), 98304u));
            s2[j] = lys2[j] * (1.0 / 64.0) - log(-log((double)u));
          }
          double g; argmax_gap6(s2, argY, g);
        }
        argY = __shfl(argY, 0);
        bYf = 16.0f * idx_to_bits(argY);
        if (k == 0) {
          out[O_yba + m] = bYf;
#pragma unroll
          for (int j = 0; j < 6; ++j) out[O_wy + m * 6 + j] = (j == argY) ? 1.0f : 0.0f;
        }
      } else {
        bYf = out[O_yba + m];
      }

      out[O_eb + (size_t)m * 64 + k] = (bYf * 0.015625f + bHf) + bDf;
    }
    __syncthreads();  // headP64/actB64 safe before next mi reuses them
  }
}

// ---------------------------------------------------------------- LSQ quant
__device__ __forceinline__ int bits_to_idx(int bits) {
  return (bits <= 8) ? ((bits >> 1) - 1) : ((bits == 12) ? 4 : 5);
}

__device__ __forceinline__ float lsq1(float x, float ssv, float qn, float qp) {
  float t = x / ssv;
  t = fminf(fmaxf(t, qn), qp);
  return rintf(t) * ssv;
}

__global__ void k3_Hq(const float* __restrict__ Hm, const float* __restrict__ ss,
                      const float* __restrict__ Hbits, float* __restrict__ outHq) {
  const int id = blockIdx.x * blockDim.x + threadIdx.x;
  if (id >= 8388608) return;
  const int k = id & 63;
  const int m = id >> 9;
  const int bits = (int)Hbits[(size_t)m * 64 + k] >> 4;
  const int i = bits_to_idx(bits);
  const float ssv = ss[6 + i];
  const float qp = (float)((1 << (bits - 1)) - 1);
  const float qn = -(float)(1 << (bits - 1));
  const float2 x = ((const float2*)Hm)[id];
  float2 o;
  o.x = lsq1(x.x, ssv, qn, qp);
  o.y = lsq1(x.y, ssv, qn, qp);
  ((float2*)outHq)[id] = o;
}

__global__ void k4_vq(const float* __restrict__ v, const float* __restrict__ ss,
                      const float* __restrict__ dbits, float* __restrict__ outvq) {
  const int id = blockIdx.x * blockDim.x + threadIdx.x;
  if (id >= 1048576) return;
  const int bits = (int)dbits[id] >> 1;
  const int i = bits_to_idx(bits);
  const float ssv = ss[12 + i];
  const float qp = (float)((1 << (bits - 1)) - 1);
  const float qn = -(float)(1 << (bits - 1));
  const float2 x = ((const float2*)v)[id];
  float2 o;
  o.x = lsq1(x.x, ssv, qn, qp);
  o.y = lsq1(x.y, ssv, qn, qp);
  ((float2*)outvq)[id] = o;
}

__global__ void k5_yq(const float* __restrict__ y, const float* __restrict__ ss,
                      const float* __restrict__ ybits, float* __restrict__ outyq) {
  const int id = blockIdx.x * blockDim.x + threadIdx.x;
  if (id >= 131072) return;
  const int m = id >> 3;
  const int bits = (int)ybits[m] >> 4;
  const int i = bits_to_idx(bits);
  const float ssv = ss[i];
  const float qp = (float)((1 << (bits - 1)) - 1);
  const float qn = -(float)(1 << (bits - 1));
  const float2 x = ((const float2*)y)[id];
  float2 o;
  o.x = lsq1(x.x, ssv, qn, qp);
  o.y = lsq1(x.y, ssv, qn, qp);
  ((float2*)outyq)[id] = o;
}

// ---------------------------------------------------------------- launch
extern "C" void kernel_launch(void* const* d_in, const int* in_sizes, int n_in,
                              void* d_out, int out_size, void* d_ws, size_t ws_size,
                              hipStream_t stream) {
  const float* v   = (const float*)d_in[0];
  const float* Hm  = (const float*)d_in[1];
  const float* y   = (const float*)d_in[2];
  const float* snr = (const float*)d_in[3];
  const float* w1  = (const float*)d_in[4];
  const float* b1  = (const float*)d_in[5];
  const float* w2  = (const float*)d_in[6];
  const float* b2  = (const float*)d_in[7];
  const float* w3  = (const float*)d_in[8];
  const float* b3  = (const float*)d_in[9];
  const float* wy  = (const float*)d_in[10];
  const float* by  = (const float*)d_in[11];
  const float* wh  = (const float*)d_in[12];
  const float* bh  = (const float*)d_in[13];
  const float* wd  = (const float*)d_in[14];
  const float* bd  = (const float*)d_in[15];
  const float* sy  = (const float*)d_in[16];
  const float* sH  = (const float*)d_in[17];
  const float* sd  = (const float*)d_in[18];

  float* out = (float*)d_out;

  double* ws_partial = (double*)d_ws;
  double* ws_hpmean  = ws_partial + 32768;
  float*  ws_ss      = (float*)(ws_hpmean + 4096);
  uint32_t* ws_keys  = (uint32_t*)(ws_ss + 18);

  // transposed weights live in the H_q out region until k3 overwrites it
  float* wsT = out + O_Hq;

  k0_setup<<<1, 64, 0, stream>>>(sy, sH, sd, ws_ss, ws_keys);
  k0w_transpose<<<16, 256, 0, stream>>>(w1, w2, w3, wy, wh, wd, wsT);
  k1a_hpower_partial<<<512, 128, 0, stream>>>(Hm, ws_partial);
  k1b_hpmean<<<16, 256, 0, stream>>>(ws_partial, ws_hpmean);
  k2_main<<<BL / 4, 256, 0, stream>>>(v, Hm, y, snr, b1, b2, b3, by, bh, bd,
                                      wsT, ws_hpmean, ws_keys, out);
  kfix<<<BL / 8, 256, 0, stream>>>(v, Hm, y, snr, w1, b1, w2, b2, w3, b3,
                                   wy, by, wh, bh, wd, bd, ws_hpmean, ws_keys, out);
  k3_Hq<<<32768, 256, 0, stream>>>(Hm, ws_ss, out + O_Hbl, out + O_Hq);
  k4_vq<<<4096, 256, 0, stream>>>(v, ws_ss, out + O_dbl, out + O_vq);
  k5_yq<<<512, 256, 0, stream>>>(y, ws_ss, out + O_yba, out + O_yq);
}